// Round 7
// baseline (388550.537 us; speedup 1.0000x reference)
//
#include <hip/hip_runtime.h>
#include <hip/hip_bf16.h>

// Persistent cooperative RNN kernel for MI355X (gfx950) — barrier-free
// epoch-tagged dataflow, v2: minimal-hop edition.
// 256 WGs x 512 threads, 1 WG/CU (~153KB LDS). Each WG owns 4 hidden rows =>
// 16 gate rows of every 4H weight matrix. 5 LIC exchanges per step
// (HENC -> DHX -> DD1 -> DD2 -> DD3), each an epoch-tagged (f32,u32) pair
// vector stored with agent-scope 64-bit atomics and polled by ONE wave per WG
// (batched sc0sc1 16B loads + s_sleep backoff), then LDS-broadcast.
// cls/fut small matvecs are computed LOCALLY in every WG from VGPR-resident
// weight rows (cf[8][16] per thread) — no split-K, no reducers, no extra RTs.
// Enc weights f32 in LDS, dec weights bf16 in LDS, fus_W rows in VGPRs.

typedef unsigned short u16t;
typedef unsigned int u32t;
typedef unsigned long long u64t;

#define TSTEPS 2045
#define NWG 256
#define NTHR 512
#define SPINCAP 16384

// d_ws float offsets: six [2 parity][1024 pairs] tagged vectors
#define HENC  0
#define CENC  4096
#define DHX   8192
#define DD1   12288
#define DD2   16384
#define DD3   20480

struct Params {
  const void *X, *eWih, *eWhh, *ebih, *ebhh, *dWih, *dWhh, *dbih, *dbhh,
             *hxW, *hxb, *cxW, *cxb, *fusW, *fusb_g, *futW, *futb_g, *clsW, *clsb_g;
  float* ws;
  void* out;
};

struct SharedMem {
  alignas(16) float encW[16 * 1152];   // [row][Wih(128)|Whh(1024)] f32, 73728B
  alignas(16) u16t  decW[16 * 2048];   // [row][Wih(1024)|Whh(1024)] bf16, 65536B
  alignas(16) float xs[2048];          // staged vectors for dots
  alignas(16) float dd[1024];          // dh3 staging at R1
  float clsb[64], futb[64], fut_acc[64], dsbuf[64], fv3[64];
  float bias_e[16], bias_d[16], g16[16];
  float h4[4], dcx_s[4], encc[4], hxb4[4], cxb4[4];
  int bail;
  int badcnt;
};

__device__ __forceinline__ float bfu(u16t u){
  union { u32t i; float f; } v; v.i = ((u32t)u) << 16; return v.f;
}
__device__ __forceinline__ u32t fbits(float f){
  union { float f; u32t u; } c; c.f = f; return c.u;
}
__device__ __forceinline__ u16t bf16bits(float v){
  __hip_bfloat16 b = __float2bfloat16(v);
  union { __hip_bfloat16 b; u16t u; } c; c.b = b; return c.u;
}
template<bool F32>
__device__ __forceinline__ float ldE(const void* p, int i){
  if (F32) return ((const float*)p)[i];
  return bfu(((const u16t*)p)[i]);
}
template<bool F32>
__device__ __forceinline__ u16t ldB(const void* p, int i){
  if (F32) return bf16bits(((const float*)p)[i]);
  return ((const u16t*)p)[i];
}
template<bool F32>
__device__ __forceinline__ void stO(void* p, int i, float v){
  if (F32) ((float*)p)[i] = v;
  else     ((u16t*)p)[i] = bf16bits(v);
}
__device__ __forceinline__ float sigm(float x){ return 1.f / (1.f + __expf(-x)); }
__device__ __forceinline__ float tanhx(float x){
  float e = __expf(-2.f * fabsf(x));
  float t = (1.f - e) / (1.f + e);
  return copysignf(t, x);
}
// Tagged-pair store: (value, epoch) as one 64-bit agent-scope atomic.
__device__ __forceinline__ void stp(float* rowbase, int idx, float v, u32t ep){
  u64t u = (u64t)fbits(v) | ((u64t)ep << 32);
  __hip_atomic_store((u64t*)rowbase + idx, u,
                     __ATOMIC_RELAXED, __HIP_MEMORY_SCOPE_AGENT);
}
// 8 coherent 16B loads, single wait.
__device__ __forceinline__ void ld4c8(const float* p0, const float* p1,
                                      const float* p2, const float* p3,
                                      const float* p4, const float* p5,
                                      const float* p6, const float* p7,
                                      float4& r0, float4& r1, float4& r2, float4& r3,
                                      float4& r4, float4& r5, float4& r6, float4& r7){
  asm volatile(
    "global_load_dwordx4 %0, %8, off sc0 sc1\n\t"
    "global_load_dwordx4 %1, %9, off sc0 sc1\n\t"
    "global_load_dwordx4 %2, %10, off sc0 sc1\n\t"
    "global_load_dwordx4 %3, %11, off sc0 sc1\n\t"
    "global_load_dwordx4 %4, %12, off sc0 sc1\n\t"
    "global_load_dwordx4 %5, %13, off sc0 sc1\n\t"
    "global_load_dwordx4 %6, %14, off sc0 sc1\n\t"
    "global_load_dwordx4 %7, %15, off sc0 sc1\n\t"
    "s_waitcnt vmcnt(0)"
    : "=&v"(r0), "=&v"(r1), "=&v"(r2), "=&v"(r3),
      "=&v"(r4), "=&v"(r5), "=&v"(r6), "=&v"(r7)
    : "v"(p0), "v"(p1), "v"(p2), "v"(p3), "v"(p4), "v"(p5), "v"(p6), "v"(p7)
    : "memory");
}

// Wave-scope poll of a 1024-pair tagged vector into LDS dst[1024].
// One wave (64 lanes): 8 batched quads per lane, s_sleep backoff on miss.
__device__ __forceinline__ void poll_vec(const float* base, u32t ep,
                                         float* dst, int lane64, int* bail){
  const float* q = base + 32 * lane64;
  float4 r0,r1,r2,r3,r4,r5,r6,r7;
  int sp = 0;
  for (;;){
    ld4c8(q, q+4, q+8, q+12, q+16, q+20, q+24, q+28, r0,r1,r2,r3,r4,r5,r6,r7);
    bool ok = fbits(r0.y)==ep && fbits(r0.w)==ep && fbits(r1.y)==ep && fbits(r1.w)==ep
           && fbits(r2.y)==ep && fbits(r2.w)==ep && fbits(r3.y)==ep && fbits(r3.w)==ep
           && fbits(r4.y)==ep && fbits(r4.w)==ep && fbits(r5.y)==ep && fbits(r5.w)==ep
           && fbits(r6.y)==ep && fbits(r6.w)==ep && fbits(r7.y)==ep && fbits(r7.w)==ep;
    if (ok) break;
    if (*bail) break;
    if (++sp > SPINCAP){ *bail = 1; break; }
    __builtin_amdgcn_s_sleep(1);
  }
  float* d = dst + 16 * lane64;
  d[0]=r0.x;  d[1]=r0.z;  d[2]=r1.x;  d[3]=r1.z;
  d[4]=r2.x;  d[5]=r2.z;  d[6]=r3.x;  d[7]=r3.z;
  d[8]=r4.x;  d[9]=r4.z;  d[10]=r5.x; d[11]=r5.z;
  d[12]=r6.x; d[13]=r6.z; d[14]=r7.x; d[15]=r7.z;
}

// Half-wave (32 lanes) dot of GLOBAL weight row with f32 x (LDS).
template<bool F32>
__device__ __forceinline__ float hw_dot(const void* wbase, long off,
                                        const float* __restrict__ x,
                                        int K, int lane){
  float acc = 0.f;
  if (F32){
    const float* w = (const float*)wbase + off;
    for (int c = lane * 4; c < K; c += 128){
      float4 wv = *(const float4*)(w + c);
      float4 xv = *(const float4*)(x + c);
      acc = fmaf(wv.x, xv.x, acc); acc = fmaf(wv.y, xv.y, acc);
      acc = fmaf(wv.z, xv.z, acc); acc = fmaf(wv.w, xv.w, acc);
    }
  } else {
    const u16t* w = (const u16t*)wbase + off;
    for (int c = lane * 4; c < K; c += 128){
      ushort4 wv = *(const ushort4*)(w + c);
      float4  xv = *(const float4*)(x + c);
      acc = fmaf(bfu(wv.x), xv.x, acc); acc = fmaf(bfu(wv.y), xv.y, acc);
      acc = fmaf(bfu(wv.z), xv.z, acc); acc = fmaf(bfu(wv.w), xv.w, acc);
    }
  }
  #pragma unroll
  for (int o = 16; o; o >>= 1) acc += __shfl_xor(acc, o, 64);
  return acc;
}

__device__ __forceinline__ float lds_dot_f32(const float* __restrict__ w,
                                             const float* __restrict__ x,
                                             int K, int lane){
  float acc = 0.f;
  for (int c = lane * 4; c < K; c += 128){
    float4 wv = *(const float4*)(w + c);
    float4 xv = *(const float4*)(x + c);
    acc = fmaf(wv.x, xv.x, acc); acc = fmaf(wv.y, xv.y, acc);
    acc = fmaf(wv.z, xv.z, acc); acc = fmaf(wv.w, xv.w, acc);
  }
  #pragma unroll
  for (int o = 16; o; o >>= 1) acc += __shfl_xor(acc, o, 64);
  return acc;
}

__device__ __forceinline__ float lds_dot_bf16(const u16t* __restrict__ w,
                                              const float* __restrict__ x,
                                              int K, int lane){
  float acc = 0.f;
  for (int c = lane * 8; c < K; c += 256){
    uint4  wv = *(const uint4*)(w + c);
    float4 x0 = *(const float4*)(x + c);
    float4 x1 = *(const float4*)(x + c + 4);
    acc = fmaf(bfu((u16t)(wv.x & 0xffff)), x0.x, acc);
    acc = fmaf(bfu((u16t)(wv.x >> 16)),    x0.y, acc);
    acc = fmaf(bfu((u16t)(wv.y & 0xffff)), x0.z, acc);
    acc = fmaf(bfu((u16t)(wv.y >> 16)),    x0.w, acc);
    acc = fmaf(bfu((u16t)(wv.z & 0xffff)), x1.x, acc);
    acc = fmaf(bfu((u16t)(wv.z >> 16)),    x1.y, acc);
    acc = fmaf(bfu((u16t)(wv.w & 0xffff)), x1.z, acc);
    acc = fmaf(bfu((u16t)(wv.w >> 16)),    x1.w, acc);
  }
  #pragma unroll
  for (int o = 16; o; o >>= 1) acc += __shfl_xor(acc, o, 64);
  return acc;
}

// Local cls/fut matvec from VGPR-resident rows: half-wave hw owns rows
// 8hw..8hw+7 of M=[clsW;futW]; lane owns cols {8l..8l+7} in each 256-chunk.
// x = staged dh vector (LDS, 1024 f32). Results -> dsbuf (+clsb) / fv3 (relu+futb).
__device__ __forceinline__ void local_clsfut(SharedMem& S, const float* __restrict__ x,
                                             const u32t (&cf)[8][16], int hw, int lane){
  float xv[32];
  #pragma unroll
  for (int c = 0; c < 4; ++c){
    *(float4*)&xv[c*8]     = *(const float4*)&x[c*256 + 8*lane];
    *(float4*)&xv[c*8 + 4] = *(const float4*)&x[c*256 + 8*lane + 4];
  }
  #pragma unroll
  for (int r = 0; r < 8; ++r){
    float a = 0.f;
    #pragma unroll
    for (int c = 0; c < 4; ++c){
      #pragma unroll
      for (int j = 0; j < 4; ++j){
        u32t pk = cf[r][c*4+j];
        a = fmaf(bfu((u16t)(pk & 0xffff)), xv[c*8 + 2*j], a);
        a = fmaf(bfu((u16t)(pk >> 16)),    xv[c*8 + 2*j + 1], a);
      }
    }
    #pragma unroll
    for (int m = 16; m; m >>= 1) a += __shfl_xor(a, m, 64);
    if (lane == 0){
      int o = hw * 8 + r;
      if (o < 64) S.dsbuf[o] = a + S.clsb[o];
      else        S.fv3[o - 64] = fmaxf(a + S.futb[o - 64], 0.f);
    }
  }
}

template<bool F32>
__device__ void run(const Params& p, SharedMem& S){
  const int tid    = threadIdx.x;
  const int w      = blockIdx.x;
  const int wv     = tid >> 6;          // wave 0..7
  const int lane64 = tid & 63;
  const int hw     = tid >> 5;          // half-wave 0..15 -> one gate row each
  const int lane   = tid & 31;
  const long grow  = (long)((hw >> 2) * 1024 + 4 * w + (hw & 3));  // gate row
  float* ws = p.ws;

  // ---------- startup: stage per-WG weights ----------
  {
    float* er = S.encW + hw * 1152;
    for (int c = lane; c < 128; c += 32)  er[c]       = ldE<F32>(p.eWih, (int)(grow * 128 + c));
    for (int c = lane; c < 1024; c += 32) er[128 + c] = ldE<F32>(p.eWhh, (int)(grow * 1024 + c));
    u16t* dr = S.decW + hw * 2048;
    for (int c = lane; c < 1024; c += 32){
      dr[c]        = ldB<F32>(p.dWih, (int)(grow * 1024 + c));
      dr[1024 + c] = ldB<F32>(p.dWhh, (int)(grow * 1024 + c));
    }
  }
  // cls/fut rows -> VGPRs (cf[8][16]): row o=8hw+r, cols c*256+8*lane+2j(+1)
  u32t cf[8][16];
  #pragma unroll
  for (int r = 0; r < 8; ++r){
    int o = 8 * hw + r;
    const void* src = (o < 64) ? p.clsW : p.futW;
    int ro = (o < 64) ? o : o - 64;
    #pragma unroll
    for (int c = 0; c < 4; ++c){
      #pragma unroll
      for (int j = 0; j < 4; ++j){
        int k = ro * 1024 + c * 256 + 8 * lane + 2 * j;
        cf[r][c*4+j] = ((u32t)ldB<F32>(src, k + 1) << 16) | ldB<F32>(src, k);
      }
    }
  }
  // fus_W rows for this thread's two h outputs -> registers
  u32t fw[64];
  float fusb0, fusb1;
  {
    int h0 = 2 * tid, h1 = 2 * tid + 1;
    #pragma unroll
    for (int o = 0; o < 64; ++o){
      u16t lo = ldB<F32>(p.fusW, h0 * 64 + o);
      u16t hi = ldB<F32>(p.fusW, h1 * 64 + o);
      fw[o] = ((u32t)hi << 16) | lo;
    }
    fusb0 = ldE<F32>(p.fusb_g, h0);
    fusb1 = ldE<F32>(p.fusb_g, h1);
  }
  if (tid < 64){
    S.clsb[tid] = ldE<F32>(p.clsb_g, tid);
    S.futb[tid] = ldE<F32>(p.futb_g, tid);
    S.fut_acc[tid] = 0.f;
  }
  if (tid < 16){
    int gr = (tid >> 2) * 1024 + 4 * w + (tid & 3);
    S.bias_e[tid] = ldE<F32>(p.ebih, gr) + ldE<F32>(p.ebhh, gr);
    S.bias_d[tid] = ldE<F32>(p.dbih, gr) + ldE<F32>(p.dbhh, gr);
  }
  if (tid < 4){
    S.hxb4[tid] = ldE<F32>(p.hxb, 4 * w + tid);
    S.cxb4[tid] = ldE<F32>(p.cxb, 4 * w + tid);
    S.encc[tid] = 0.f;
  }
  __syncthreads();

  for (int t = 0; t < TSTEPS; ++t){
    const int  par  = t & 1;
    const int  ppar = par ^ 1;
    const u32t ep   = (u32t)(t + 1);
    const u32t epv  = (u32t)t;

    // ============ R1: encoder gates (+ local ds3/f3 from DD3) ============
    if (t > 0){
      if (wv == 0)      poll_vec(ws + HENC + ppar * 2048, epv, S.xs + 128, lane64, &S.bail);
      else if (wv == 1) poll_vec(ws + DD3  + ppar * 2048, epv, S.dd,      lane64, &S.bail);
    } else {
      for (int i = tid; i < 1024; i += NTHR) S.xs[128 + i] = 0.f;
    }
    __syncthreads();
    if (t > 0) local_clsfut(S, S.dd, cf, hw, lane);    // ds3 -> dsbuf, f3 -> fv3
    __syncthreads();
    if (tid < 64){
      S.xs[tid] = ldE<F32>(p.X, t * 64 + tid);         // fusion[0:64] = x_t
      float fv = (t > 0) ? (S.fut_acc[tid] + S.fv3[tid]) * (1.f / 3.f) : 0.f;
      S.xs[64 + tid] = fv;                             // fusion[64:128] = fut
      S.fut_acc[tid] = 0.f;
      if (w == 32 && t > 0)                            // ds3 of previous step
        stO<F32>(p.out, TSTEPS * 64 + ((t - 1) * 3 + 2) * 64 + tid, S.dsbuf[tid]);
    }
    __syncthreads();
    {
      float a = lds_dot_f32(S.encW + hw * 1152, S.xs, 1152, lane) + S.bias_e[hw];
      if (lane == 0) S.g16[hw] = a;
    }
    __syncthreads();
    if (tid < 4){
      float gi = sigm(S.g16[tid]), gf = sigm(S.g16[4 + tid]),
            gg = tanhx(S.g16[8 + tid]), go = sigm(S.g16[12 + tid]);
      float c = gf * S.encc[tid] + gi * gg;
      float h = go * tanhx(c);
      S.encc[tid] = c;
      stp(ws + HENC + par * 2048, 4 * w + tid, h, ep);
      stp(ws + CENC + par * 2048, 4 * w + tid, c, ep);
    }

    // ============ R2: heads dhx/dcx + enc_score ============
    if (wv == 0)      poll_vec(ws + HENC + par * 2048, ep, S.xs,        lane64, &S.bail);
    else if (wv == 1) poll_vec(ws + CENC + par * 2048, ep, S.xs + 1024, lane64, &S.bail);
    __syncthreads();
    if (hw < 4){
      float d = fmaxf(hw_dot<F32>(p.hxW, (long)(4 * w + hw) * 1024, S.xs, 1024, lane)
                      + S.hxb4[hw], 0.f);
      if (lane == 0) stp(ws + DHX + par * 2048, 4 * w + hw, d, ep);
    } else if (hw < 8){
      int j = hw - 4;
      float d = fmaxf(hw_dot<F32>(p.cxW, (long)(4 * w + j) * 1024, S.xs + 1024, 1024, lane)
                      + S.cxb4[j], 0.f);
      if (lane == 0) S.dcx_s[j] = d;   // decoder c, reused by all 3 iters (ref bug)
    } else if (w >= 8 && w < 16){      // enc_score: 8 WGs x 8 half-waves
      int r = (w - 8) * 8 + (hw - 8);
      float s = hw_dot<F32>(p.clsW, (long)r * 1024, S.xs, 1024, lane) + S.clsb[r];
      if (lane == 0) stO<F32>(p.out, t * 64 + r, s);
    }
    __syncthreads();   // xs reads done before R3 poll overwrites

    // ============ R3: decoder iter 1 (fusion_in = 0) ============
    if (wv == 0) poll_vec(ws + DHX + par * 2048, ep, S.xs, lane64, &S.bail);
    __syncthreads();
    {
      float a = lds_dot_bf16(S.decW + hw * 2048 + 1024, S.xs, 1024, lane) + S.bias_d[hw];
      if (lane == 0) S.g16[hw] = a;
    }
    __syncthreads();
    if (tid < 4){
      float gi = sigm(S.g16[tid]), gf = sigm(S.g16[4 + tid]),
            gg = tanhx(S.g16[8 + tid]), go = sigm(S.g16[12 + tid]);
      float c = gf * S.dcx_s[tid] + gi * gg;
      stp(ws + DD1 + par * 2048, 4 * w + tid, go * tanhx(c), ep);
    }

    // ============ R4/R5: decoder iters 2,3 ============
    for (int di = 2; di <= 3; ++di){
      const int src = (di == 2) ? DD1 : DD2;
      const int dst = (di == 2) ? DD2 : DD3;
      if (wv == 0) poll_vec(ws + src + par * 2048, ep, S.xs + 1024, lane64, &S.bail);
      __syncthreads();
      local_clsfut(S, S.xs + 1024, cf, hw, lane);      // ds_{di-1}, f_{di-1}
      __syncthreads();
      if (tid < 64){
        S.fut_acc[tid] += S.fv3[tid];
        if ((di == 2 && w == 16) || (di == 3 && w == 24))
          stO<F32>(p.out, TSTEPS * 64 + (t * 3 + (di - 2)) * 64 + tid, S.dsbuf[tid]);
      }
      {   // fusion_in = relu(fus_W @ ds + fus_b), per-thread 2 rows from VGPRs
        float a0 = fusb0, a1 = fusb1;
        #pragma unroll
        for (int o = 0; o < 64; ++o){
          float d = S.dsbuf[o];
          a0 = fmaf(bfu((u16t)(fw[o] & 0xffff)), d, a0);
          a1 = fmaf(bfu((u16t)(fw[o] >> 16)),    d, a1);
        }
        S.xs[2 * tid]     = fmaxf(a0, 0.f);
        S.xs[2 * tid + 1] = fmaxf(a1, 0.f);
      }
      __syncthreads();
      {
        float a = lds_dot_bf16(S.decW + hw * 2048, S.xs, 2048, lane) + S.bias_d[hw];
        if (lane == 0) S.g16[hw] = a;
      }
      __syncthreads();
      if (tid < 4){
        float gi = sigm(S.g16[tid]), gf = sigm(S.g16[4 + tid]),
              gg = tanhx(S.g16[8 + tid]), go = sigm(S.g16[12 + tid]);
        float c = gf * S.dcx_s[tid] + gi * gg;
        stp(ws + dst + par * 2048, 4 * w + tid, go * tanhx(c), ep);
      }
    }
  }

  // epilogue: ds3 of the final step (WG 32)
  if (w == 32){
    const int lpar = (TSTEPS - 1) & 1;
    if (wv == 0) poll_vec(ws + DD3 + lpar * 2048, (u32t)TSTEPS, S.dd, lane64, &S.bail);
    __syncthreads();
    local_clsfut(S, S.dd, cf, hw, lane);
    __syncthreads();
    if (tid < 64)
      stO<F32>(p.out, TSTEPS * 64 + ((TSTEPS - 1) * 3 + 2) * 64 + tid, S.dsbuf[tid]);
  }
}

__global__ __launch_bounds__(NTHR, 2)
void trn_persist(Params p){
  __shared__ SharedMem S;
  // ---- runtime input-dtype detection from X's bit patterns ----
  if (threadIdx.x == 0){ S.bail = 0; S.badcnt = 0; }
  __syncthreads();
  if (threadIdx.x < 256){
    u16t u = ((const u16t*)p.X)[threadIdx.x];
    int e = (u >> 7) & 0xff;
    if (e == 0 || e >= 141) atomicAdd(&S.badcnt, 1);
  }
  __syncthreads();
  if (S.badcnt >= 3) run<true>(p, S);
  else               run<false>(p, S);
}

extern "C" void kernel_launch(void* const* d_in, const int* in_sizes, int n_in,
                              void* d_out, int out_size, void* d_ws, size_t ws_size,
                              hipStream_t stream){
  Params P;
  P.X      = d_in[0];
  P.eWih   = d_in[1];
  P.eWhh   = d_in[2];
  P.ebih   = d_in[3];
  P.ebhh   = d_in[4];
  P.dWih   = d_in[5];
  P.dWhh   = d_in[6];
  P.dbih   = d_in[7];
  P.dbhh   = d_in[8];
  P.hxW    = d_in[9];
  P.hxb    = d_in[10];
  P.cxW    = d_in[11];
  P.cxb    = d_in[12];
  P.fusW   = d_in[13];
  P.fusb_g = d_in[14];
  P.futW   = d_in[15];
  P.futb_g = d_in[16];
  P.clsW   = d_in[17];
  P.clsb_g = d_in[18];
  P.ws     = (float*)d_ws;
  P.out    = d_out;

  void* args[] = { &P };
  hipLaunchCooperativeKernel((void*)trn_persist, dim3(NWG), dim3(NTHR),
                             args, 0, stream);
}